// Round 18
// baseline (440.157 us; speedup 1.0000x reference)
//
#include <hip/hip_runtime.h>
#include <hip/hip_bf16.h>

#define DD 256      // feature dim
#define NM 64       // memory slots

typedef unsigned long long u64;
typedef float v2f __attribute__((ext_vector_type(2)));

struct v2x2 { v2f lo, hi; };
static __device__ __forceinline__ v2x2 splitf4(float4 f) {
    union { float4 a; v2x2 b; } u; u.a = f; return u.b;
}

// pk: acc(pair) += splat(src0 half) * c(pair).  Bit-identical to two fmaf.
#define PK_FMA_SPLATLO(acc, q2, c2) \
    asm("v_pk_fma_f32 %0, %1, %2, %0 op_sel:[0,0,0] op_sel_hi:[0,1,1]" \
        : "+v"(acc) : "v"(q2), "v"(c2))
#define PK_FMA_SPLATHI(acc, q2, c2) \
    asm("v_pk_fma_f32 %0, %1, %2, %0 op_sel:[1,0,0] op_sel_hi:[1,1,1]" \
        : "+v"(acc) : "v"(q2), "v"(c2))

// ---------------------------------------------------------------------------
// prep_tr: wt[d][o] = W[o][d] for Wq and Wk
// ---------------------------------------------------------------------------
__global__ __launch_bounds__(256) void prep_tr(
    const float* __restrict__ Wq, const float* __restrict__ Wk,
    float* __restrict__ wqt, float* __restrict__ wkt)
{
    const int o = blockIdx.x;
    const int d = threadIdx.x;
    if (blockIdx.y == 0) wqt[d * DD + o] = Wq[o * DD + d];
    else                 wkt[d * DD + o] = Wk[o * DD + d];
}

// ---------------------------------------------------------------------------
// prep_kT: kT4[(o>>2)*(NM*4) + n*4 + (o&3)] = k[n][o]   ([og][n][4] layout)
//   k[n][o] = sum_d mem[n][d]*Wk[o][d]  (fp32, d-ascending single-acc)
//   bias[n] = fl32(max(log(imp*0.99^age), -10))
// ---------------------------------------------------------------------------
__global__ __launch_bounds__(256) void prep_kT(
    const float* __restrict__ mem, const float* __restrict__ wkt,
    const float* __restrict__ imp, const float* __restrict__ age,
    float* __restrict__ kT4, float* __restrict__ bias)
{
    const int n = blockIdx.x;
    const int o = threadIdx.x;
    const float* mrow = mem + n * DD;
    float acc = 0.f;
    for (int d = 0; d < DD; ++d)
        acc = fmaf(mrow[d], wkt[d * DD + o], acc);
    kT4[(o >> 2) * (NM * 4) + n * 4 + (o & 3)] = acc;

    if (o == 0) {
        double eff = (double)imp[n] * pow(0.99, (double)age[n]);
        float b = (float)log(eff);
        if (!(b >= -10.0f)) b = -10.0f;
        bias[n] = b;
    }
}

// ---------------------------------------------------------------------------
// qgemm_w: q = query @ Wq^T -> qout. ONE WAVE per block, 8 rows, 8 KB LDS.
// No cross-wave coupling: up to 16 independent waves/CU hide all latency.
// Chains per (row,o): d-ascending single-acc fma — bit-identical to R16/R17.
// ---------------------------------------------------------------------------
__global__ __launch_bounds__(64, 2) void qgemm_w(
    const float* __restrict__ query,   // [M][DD]
    const float4* __restrict__ wqt4,   // [DD][NM]: wqt4[d*64+l] = WqT[d][4l..4l+3]
    float* __restrict__ qout,          // [M][DD]
    int M)
{
    __shared__ float lds[8 * DD];      // 8 KB: this wave's 8 query rows
    const int l = threadIdx.x;         // 0..63
    const int row0 = blockIdx.x * 8;

    // stage 8 query rows (coalesced 1KB per row)
    {
        const float4* q4g = reinterpret_cast<const float4*>(query);
#pragma unroll
        for (int rr = 0; rr < 8; ++rr) {
            int gr = row0 + rr; if (gr > M - 1) gr = M - 1;
            *reinterpret_cast<float4*>(&lds[rr * DD + l * 4]) =
                q4g[(size_t)gr * 64 + l];
        }
    }
    __syncthreads();   // 1-wave barrier: just orders LDS writes vs reads

    // lane l owns o = 4l..4l+3 as pairs
    v2f a01[8], a23[8];
#pragma unroll
    for (int rr = 0; rr < 8; ++rr) { a01[rr] = (v2f)(0.f); a23[rr] = (v2f)(0.f); }

    {
        float4 cw0 = wqt4[0 * NM + l];
        float4 cw1 = wqt4[1 * NM + l];
        float4 cw2 = wqt4[2 * NM + l];
        float4 cw3 = wqt4[3 * NM + l];

        for (int d0 = 0; d0 < DD; d0 += 4) {
            const int dn = (d0 + 4) & (DD - 1);    // wraps on last iter
            const float4 nw0 = wqt4[(dn + 0) * NM + l];
            const float4 nw1 = wqt4[(dn + 1) * NM + l];
            const float4 nw2 = wqt4[(dn + 2) * NM + l];
            const float4 nw3 = wqt4[(dn + 3) * NM + l];
            const v2x2 c0 = splitf4(cw0), c1 = splitf4(cw1);
            const v2x2 c2 = splitf4(cw2), c3 = splitf4(cw3);
#pragma unroll
            for (int rr = 0; rr < 8; ++rr) {
                const float4 qq = *reinterpret_cast<const float4*>(
                    &lds[rr * DD + d0]);           // uniform ds_read_b128
                const v2x2 qh = splitf4(qq);
                // d-ascending per chain (bit-identical to R16):
                PK_FMA_SPLATLO(a01[rr], qh.lo, c0.lo);
                PK_FMA_SPLATLO(a23[rr], qh.lo, c0.hi);
                PK_FMA_SPLATHI(a01[rr], qh.lo, c1.lo);
                PK_FMA_SPLATHI(a23[rr], qh.lo, c1.hi);
                PK_FMA_SPLATLO(a01[rr], qh.hi, c2.lo);
                PK_FMA_SPLATLO(a23[rr], qh.hi, c2.hi);
                PK_FMA_SPLATHI(a01[rr], qh.hi, c3.lo);
                PK_FMA_SPLATHI(a23[rr], qh.hi, c3.hi);
            }
            cw0 = nw0; cw1 = nw1; cw2 = nw2; cw3 = nw3;
        }
    }

    // store q rows (coalesced 1KB per row)
#pragma unroll
    for (int rr = 0; rr < 8; ++rr) {
        const int grow = row0 + rr;
        if (grow < M) {
            float4 v; v.x = a01[rr].x; v.y = a01[rr].y; v.z = a23[rr].x; v.w = a23[rr].y;
            *reinterpret_cast<float4*>(&qout[(size_t)grow * DD + 4 * l]) = v;
        }
    }
}

// ---------------------------------------------------------------------------
// fin_w: scores -> top-k -> softmax -> attn + retrieved. ONE WAVE, 8 rows.
// Scores: lane = n; per og ONE per-lane kT4 b128 (L1-hot) shared by 8 rows;
// q via uniform ds_read. Chain per (row,n): o-ascending fma — bit-identical
// to R16's packed version. topk/Z/PV chains identical to R16.
// ---------------------------------------------------------------------------
__global__ __launch_bounds__(64, 2) void fin_w(
    const float* __restrict__ qin,     // [M][DD] (aliases out_ret)
    const float* __restrict__ mem,     // [NM][DD]
    const float4* __restrict__ kT44,   // [DD/4][NM] float4 view of kT4
    const float* __restrict__ bias,    // [NM]
    const int* __restrict__ topk_p,
    float* __restrict__ out_ret,       // [M][DD] (same buffer as qin)
    float* __restrict__ out_attn,      // [M][NM]
    int M)
{
    __shared__ float lds_q[8 * DD];    // 8 KB q rows; sel aliases after scores
    __shared__ float lds_s[8 * NM];    // 2 KB scores (rotated cols)
    int*   sel_i = (int*)lds_q;        //   [8][16]
    float* sel_w = lds_q + 8 * 16;     //   [8][16]

    const int l = threadIdx.x;         // 0..63
    const int row0 = blockIdx.x * 8;
    const int k = *topk_p;

    // stage 8 q rows (coalesced)
    {
        const float4* q4g = reinterpret_cast<const float4*>(qin);
#pragma unroll
        for (int rr = 0; rr < 8; ++rr) {
            int gr = row0 + rr; if (gr > M - 1) gr = M - 1;
            *reinterpret_cast<float4*>(&lds_q[rr * DD + l * 4]) =
                q4g[(size_t)gr * 64 + l];
        }
    }
    __syncthreads();

    // ---- scores: lane = n; sc[r] accumulates row r
    {
        const int n = l;
        const float bn = bias[n];
        float sc[8];
#pragma unroll
        for (int r = 0; r < 8; ++r) sc[r] = 0.f;

        for (int og = 0; og < DD / 4; ++og) {
            const float4 kt = kT44[og * NM + n];    // per-lane, coalesced, L1-hot
#pragma unroll
            for (int r = 0; r < 8; ++r) {
                const float4 q4 = *reinterpret_cast<const float4*>(
                    &lds_q[r * DD + og * 4]);       // uniform ds_read_b128
                float v = sc[r];
                v = fmaf(q4.x, kt.x, v);            // o-ascending chain
                v = fmaf(q4.y, kt.y, v);
                v = fmaf(q4.z, kt.z, v);
                v = fmaf(q4.w, kt.w, v);
                sc[r] = v;
            }
        }
        // write scores (rotated: col c at (c+r)&63 -> conflict-free row scans)
#pragma unroll
        for (int r = 0; r < 8; ++r)
            lds_s[r * NM + ((n + r) & 63)] = sc[r] * 0.0625f + bn;
    }
    __syncthreads();   // q dead; sel aliases into lds_q

    // ---- per-row top-k (lanes 0..7; other lanes covered by co-resident waves)
    if (l < 8) {
        const int r = l;
        float sv[NM];
#pragma unroll
        for (int n = 0; n < NM; ++n) sv[n] = lds_s[r * NM + ((n + r) & 63)];

        if (k < NM) {
            const int kk = k < 16 ? k : 16;   // dataset: k = 8
            u64 taken = 0ull;
            float mmax = 0.f, Z = 0.f;
            for (int i = 0; i < kk; ++i) {
                float m = -1.0e30f;
                int idx = 0;
#pragma unroll
                for (int n = 0; n < NM; ++n) {
                    const bool avail  = ((taken >> n) & 1ull) == 0ull;
                    const bool better = avail && (sv[n] > m);  // strict >: lowest idx ties
                    m   = better ? sv[n] : m;
                    idx = better ? n : idx;
                }
                taken |= (1ull << idx);
                if (i == 0) mmax = m;
                const float wv = expf(m - mmax);
                Z += wv;
                sel_i[r * 16 + i] = idx;
                sel_w[r * 16 + i] = wv;
            }
#pragma unroll
            for (int n = 0; n < NM; ++n) lds_s[r * NM + ((n + r) & 63)] = 0.f;
            for (int i = 0; i < kk; ++i) {
                const float wz = sel_w[r * 16 + i] / Z;
                sel_w[r * 16 + i] = wz;
                lds_s[r * NM + ((sel_i[r * 16 + i] + r) & 63)] = wz;
            }
        } else {
            float m = -1.0e30f;
#pragma unroll
            for (int n = 0; n < NM; ++n) m = sv[n] > m ? sv[n] : m;
            float Z = 0.f;
#pragma unroll
            for (int n = 0; n < NM; ++n) Z += expf(sv[n] - m);
#pragma unroll
            for (int n = 0; n < NM; ++n) lds_s[r * NM + ((n + r) & 63)] = expf(sv[n] - m) / Z;
        }
    }
    __syncthreads();

    // ---- attn stores (lane = n, coalesced)
#pragma unroll
    for (int r = 0; r < 8; ++r) {
        const int grow = row0 + r;
        if (grow < M) out_attn[(size_t)grow * NM + l] = lds_s[r * NM + ((l + r) & 63)];
    }

    // ---- retrieved (PV): lane = d-quad
    {
        const float4* mem4 = reinterpret_cast<const float4*>(mem);   // [NM][64]
        const int kk = k < 16 ? k : 16;
#pragma unroll 1
        for (int r = 0; r < 8; ++r) {
            const int grow = row0 + r;
            if (grow >= M) continue;
            float4 acc; acc.x = 0.f; acc.y = 0.f; acc.z = 0.f; acc.w = 0.f;
            if (k < NM) {
                for (int i = 0; i < kk; ++i) {
                    const int   mi = sel_i[r * 16 + i];      // uniform ds
                    const float wz = sel_w[r * 16 + i];
                    const float4 mv = mem4[mi * 64 + l];     // coalesced, L1-hot
                    acc.x = fmaf(wz, mv.x, acc.x);           // rank-ascending chain
                    acc.y = fmaf(wz, mv.y, acc.y);
                    acc.z = fmaf(wz, mv.z, acc.z);
                    acc.w = fmaf(wz, mv.w, acc.w);
                }
            } else {
                for (int n = 0; n < NM; ++n) {
                    const float wz = lds_s[r * NM + ((n + r) & 63)];
                    const float4 mv = mem4[n * 64 + l];
                    acc.x = fmaf(wz, mv.x, acc.x);           // n-ascending chain
                    acc.y = fmaf(wz, mv.y, acc.y);
                    acc.z = fmaf(wz, mv.z, acc.z);
                    acc.w = fmaf(wz, mv.w, acc.w);
                }
            }
            *reinterpret_cast<float4*>(&out_ret[(size_t)grow * DD + 4 * l]) = acc;
        }
    }
}

// ---------------------------------------------------------------------------
extern "C" void kernel_launch(void* const* d_in, const int* in_sizes, int n_in,
                              void* d_out, int out_size, void* d_ws, size_t ws_size,
                              hipStream_t stream) {
    const float* query      = (const float*)d_in[0];
    const float* memory     = (const float*)d_in[1];
    const float* importance = (const float*)d_in[2];
    const float* age        = (const float*)d_in[3];
    const float* Wq         = (const float*)d_in[4];
    const float* Wk         = (const float*)d_in[5];
    const int*   topk       = (const int*)d_in[6];

    const int M = in_sizes[0] / DD;   // B*S = 131072

    float* kT4  = (float*)d_ws;                      // 64 KB [og][n][4]
    float* bias = kT4 + (size_t)DD * NM;             // [NM]
    float* wqt  = bias + 64;                         // [DD][DD] = 256 KB
    float* wkt  = wqt + (size_t)DD * DD;             // [DD][DD] = 256 KB

    hipLaunchKernelGGL(prep_tr, dim3(DD, 2), dim3(DD), 0, stream,
                       Wq, Wk, wqt, wkt);
    hipLaunchKernelGGL(prep_kT, dim3(NM), dim3(DD), 0, stream,
                       memory, wkt, importance, age, kT4, bias);

    float* out_ret  = (float*)d_out;
    float* out_attn = out_ret + (size_t)M * DD;

    const int nblk = (M + 7) / 8;
    // q staged through out_ret; fin_w reads its own rows before overwriting.
    hipLaunchKernelGGL(qgemm_w, dim3(nblk), dim3(64), 0, stream,
                       query, (const float4*)wqt, out_ret, M);
    hipLaunchKernelGGL(fin_w, dim3(nblk), dim3(64), 0, stream,
                       out_ret, memory, (const float4*)kT4, bias, topk,
                       out_ret, out_attn, M);
}

// Round 19
// 398.193 us; speedup vs baseline: 1.1054x; 1.1054x over previous
//
#include <hip/hip_runtime.h>
#include <hip/hip_bf16.h>

#define DD 256      // feature dim
#define NM 64       // memory slots

typedef unsigned long long u64;
typedef float v2f __attribute__((ext_vector_type(2)));

struct v2x2 { v2f lo, hi; };
static __device__ __forceinline__ v2x2 splitf4(float4 f) {
    union { float4 a; v2x2 b; } u; u.a = f; return u.b;
}

// pk: acc(pair) += splat(src0 half) * c(pair).  Bit-identical to two fmaf.
#define PK_FMA_SPLATLO(acc, q2, c2) \
    asm("v_pk_fma_f32 %0, %1, %2, %0 op_sel:[0,0,0] op_sel_hi:[0,1,1]" \
        : "+v"(acc) : "v"(q2), "v"(c2))
#define PK_FMA_SPLATHI(acc, q2, c2) \
    asm("v_pk_fma_f32 %0, %1, %2, %0 op_sel:[1,0,0] op_sel_hi:[1,1,1]" \
        : "+v"(acc) : "v"(q2), "v"(c2))

// ---------------------------------------------------------------------------
// prep_tr: wt[d][o] = W[o][d] for Wq and Wk
// ---------------------------------------------------------------------------
__global__ __launch_bounds__(256) void prep_tr(
    const float* __restrict__ Wq, const float* __restrict__ Wk,
    float* __restrict__ wqt, float* __restrict__ wkt)
{
    const int o = blockIdx.x;
    const int d = threadIdx.x;
    if (blockIdx.y == 0) wqt[d * DD + o] = Wq[o * DD + d];
    else                 wkt[d * DD + o] = Wk[o * DD + d];
}

// ---------------------------------------------------------------------------
// prep_kT: kT4[(o>>2)*(NM*4) + n*4 + (o&3)] = k[n][o]   ([og][n][4] layout)
//   k[n][o] = sum_d mem[n][d]*Wk[o][d]  (fp32, d-ascending single-acc)
//   bias[n] = fl32(max(log(imp*0.99^age), -10))
// ---------------------------------------------------------------------------
__global__ __launch_bounds__(256) void prep_kT(
    const float* __restrict__ mem, const float* __restrict__ wkt,
    const float* __restrict__ imp, const float* __restrict__ age,
    float* __restrict__ kT4, float* __restrict__ bias)
{
    const int n = blockIdx.x;
    const int o = threadIdx.x;
    const float* mrow = mem + n * DD;
    float acc = 0.f;
    for (int d = 0; d < DD; ++d)
        acc = fmaf(mrow[d], wkt[d * DD + o], acc);
    kT4[(o >> 2) * (NM * 4) + n * 4 + (o & 3)] = acc;

    if (o == 0) {
        double eff = (double)imp[n] * pow(0.99, (double)age[n]);
        float b = (float)log(eff);
        if (!(b >= -10.0f)) b = -10.0f;
        bias[n] = b;
    }
}

// ---------------------------------------------------------------------------
// qgemm4: q = query @ Wq^T -> qout. 256 thr / 32 rows / 48 KB LDS.
// wqt staged through a 16 KB LDS DOUBLE-BUFFER in 8-d chunks: loads for
// chunk c+1 issue at iteration top and land in LDS behind the barrier —
// the compiler CANNOT sink them to the use point (R17 lesson: register
// prefetch gets VGPR-squeezed away; VGPR stayed 44). 512 cyc of pk_fma
// covers the ~200-400 cyc L2 latency. wqt L2 traffic also halves.
// Chains per (row,o): d-ascending single-acc fma — bit-identical to R18.
// ---------------------------------------------------------------------------
__global__ __launch_bounds__(256, 2) void qgemm4(
    const float* __restrict__ query,   // [M][DD]
    const float4* __restrict__ wqt4,   // [DD][NM]: wqt4[d*64+l] = WqT[d][4l..4l+3]
    float* __restrict__ qout,          // [M][DD]
    int M)
{
    __shared__ float q_lds[32 * DD];        // 32 KB query rows
    __shared__ float wq_lds[2][8 * 256];    // 16 KB dbuf: [d_local][o]

    const int t = threadIdx.x;
    const int l = t & 63;
    const int w = __builtin_amdgcn_readfirstlane((int)(t >> 6));  // 0..3
    const int row0 = blockIdx.x * 32;

    // stage 32 query rows (coalesced)
    {
        const float4* q4g = reinterpret_cast<const float4*>(query);
#pragma unroll
        for (int i = 0; i < 8; ++i) {
            const int idx = i * 256 + t;
            const int r = idx >> 6, c4 = idx & 63;
            int gr = row0 + r; if (gr > M - 1) gr = M - 1;
            *reinterpret_cast<float4*>(&q_lds[r * DD + c4 * 4]) =
                q4g[(size_t)gr * 64 + c4];
        }
    }
    // stage wqt chunk 0 (d = 0..7): 512 float4s, thread t takes #t and #t+256
    {
        const float4 s0 = wqt4[t];
        const float4 s1 = wqt4[256 + t];
        reinterpret_cast<float4*>(wq_lds[0])[t]       = s0;
        reinterpret_cast<float4*>(wq_lds[0])[256 + t] = s1;
    }
    __syncthreads();

    // wave w rows 8w..8w+7; lane l owns o = 4l..4l+3 as pairs
    v2f a01[8], a23[8];
#pragma unroll
    for (int rr = 0; rr < 8; ++rr) { a01[rr] = (v2f)(0.f); a23[rr] = (v2f)(0.f); }

    const float* qbase = &q_lds[(w * 8) * DD];

    for (int c = 0; c < 32; ++c) {
        // issue loads for chunk c+1 (results consumed only at the LDS write
        // below -> full compute body covers the latency; wraps on last iter)
        const int cn = (c + 1) & 31;
        const float4 n0 = wqt4[cn * 512 + t];
        const float4 n1 = wqt4[cn * 512 + 256 + t];

        // compute chunk c (global d = 8c .. 8c+7) from wq_lds[c&1]
        {
            const float4* wb = reinterpret_cast<const float4*>(wq_lds[c & 1]);
            float4 cw[8];
#pragma unroll
            for (int i = 0; i < 8; ++i) cw[i] = wb[i * 64 + l];   // b128, conflict-free
            const v2x2 c0 = splitf4(cw[0]), c1 = splitf4(cw[1]);
            const v2x2 c2 = splitf4(cw[2]), c3 = splitf4(cw[3]);
            const v2x2 c4 = splitf4(cw[4]), c5 = splitf4(cw[5]);
            const v2x2 c6 = splitf4(cw[6]), c7 = splitf4(cw[7]);
#pragma unroll
            for (int rr = 0; rr < 8; ++rr) {
                const float4 qqA = *reinterpret_cast<const float4*>(
                    qbase + rr * DD + c * 8);          // uniform ds_read_b128
                const float4 qqB = *reinterpret_cast<const float4*>(
                    qbase + rr * DD + c * 8 + 4);
                const v2x2 qA = splitf4(qqA);
                const v2x2 qB = splitf4(qqB);
                // d-ascending per chain (bit-identical to R17/R18):
                PK_FMA_SPLATLO(a01[rr], qA.lo, c0.lo);   // d = 8c
                PK_FMA_SPLATLO(a23[rr], qA.lo, c0.hi);
                PK_FMA_SPLATHI(a01[rr], qA.lo, c1.lo);   // 8c+1
                PK_FMA_SPLATHI(a23[rr], qA.lo, c1.hi);
                PK_FMA_SPLATLO(a01[rr], qA.hi, c2.lo);   // 8c+2
                PK_FMA_SPLATLO(a23[rr], qA.hi, c2.hi);
                PK_FMA_SPLATHI(a01[rr], qA.hi, c3.lo);   // 8c+3
                PK_FMA_SPLATHI(a23[rr], qA.hi, c3.hi);
                PK_FMA_SPLATLO(a01[rr], qB.lo, c4.lo);   // 8c+4
                PK_FMA_SPLATLO(a23[rr], qB.lo, c4.hi);
                PK_FMA_SPLATHI(a01[rr], qB.lo, c5.lo);   // 8c+5
                PK_FMA_SPLATHI(a23[rr], qB.lo, c5.hi);
                PK_FMA_SPLATLO(a01[rr], qB.hi, c6.lo);   // 8c+6
                PK_FMA_SPLATLO(a23[rr], qB.hi, c6.hi);
                PK_FMA_SPLATHI(a01[rr], qB.hi, c7.lo);   // 8c+7
                PK_FMA_SPLATHI(a23[rr], qB.hi, c7.hi);
            }
        }
        // write next chunk into the buffer last read at iter c-1 (all waves
        // past that read: end-of-(c-1) barrier). vmcnt wait lands HERE.
        {
            float4* dst = reinterpret_cast<float4*>(wq_lds[(c + 1) & 1]);
            dst[t]       = n0;
            dst[256 + t] = n1;
        }
        __syncthreads();
    }

    // store q rows (coalesced 1KB per row)
#pragma unroll
    for (int rr = 0; rr < 8; ++rr) {
        const int grow = row0 + w * 8 + rr;
        if (grow < M) {
            float4 v; v.x = a01[rr].x; v.y = a01[rr].y; v.z = a23[rr].x; v.w = a23[rr].y;
            *reinterpret_cast<float4*>(&qout[(size_t)grow * DD + 4 * l]) = v;
        }
    }
}

// ---------------------------------------------------------------------------
// scores_k: raw biased scores -> out_attn (scratch; fp32 roundtrip exact).
// 256 thr / 32 rows / 32 KB LDS -> high residency. lane = n; per og one
// coalesced per-lane kT load (L1-hot) + uniform q ds_reads.
// Chain per (row,n): o-ascending fma — bit-identical to R18 fin_w.
// ---------------------------------------------------------------------------
__global__ __launch_bounds__(256, 2) void scores_k(
    const float* __restrict__ qin,     // [M][DD] (= out_ret)
    const float4* __restrict__ kT44,   // [DD/4][NM]
    const float* __restrict__ bias,    // [NM]
    float* __restrict__ sout,          // [M][NM] (= out_attn)
    int M)
{
    __shared__ float q_lds[32 * DD];   // 32 KB
    const int t = threadIdx.x;
    const int l = t & 63;
    const int w = __builtin_amdgcn_readfirstlane((int)(t >> 6));  // 0..3
    const int row0 = blockIdx.x * 32;

    {
        const float4* q4g = reinterpret_cast<const float4*>(qin);
#pragma unroll
        for (int i = 0; i < 8; ++i) {
            const int idx = i * 256 + t;
            const int r = idx >> 6, c4 = idx & 63;
            int gr = row0 + r; if (gr > M - 1) gr = M - 1;
            *reinterpret_cast<float4*>(&q_lds[r * DD + c4 * 4]) =
                q4g[(size_t)gr * 64 + c4];
        }
    }
    __syncthreads();

    const int n = l;
    const float bn = bias[n];
    float sc[8];
#pragma unroll
    for (int r = 0; r < 8; ++r) sc[r] = 0.f;

    const float* qbase = &q_lds[(w * 8) * DD];
    for (int og = 0; og < DD / 4; ++og) {
        const float4 kt = kT44[og * NM + n];       // coalesced, L1-hot
#pragma unroll
        for (int r = 0; r < 8; ++r) {
            const float4 q4 = *reinterpret_cast<const float4*>(
                qbase + r * DD + og * 4);          // uniform ds_read_b128
            float v = sc[r];
            v = fmaf(q4.x, kt.x, v);               // o-ascending chain
            v = fmaf(q4.y, kt.y, v);
            v = fmaf(q4.z, kt.z, v);
            v = fmaf(q4.w, kt.w, v);
            sc[r] = v;
        }
    }
#pragma unroll
    for (int r = 0; r < 8; ++r) {
        const int grow = row0 + w * 8 + r;
        if (grow < M) sout[(size_t)grow * NM + n] = sc[r] * 0.0625f + bn;
    }
}

// ---------------------------------------------------------------------------
// fin3: read raw scores (out_attn) -> topk (THREAD PER ROW, 128 parallel)
// -> final attn (overwrite out_attn, block-local) + retrieved (overwrite
// out_ret's q rows, block-local). topk/Z/PV chains bit-identical to R18.
// ---------------------------------------------------------------------------
#define FR 128    // rows per fin3 block
__global__ __launch_bounds__(256, 2) void fin3(
    const float* __restrict__ mem,     // [NM][DD]
    const int* __restrict__ topk_p,
    float* __restrict__ out_ret,       // [M][DD]
    float* __restrict__ out_attn,      // [M][NM] (raw scores in, attn out)
    int M)
{
    __shared__ float s_lds[FR * NM];   // 32 KB rotated scores
    __shared__ int   sel_i[FR * 16];   // 8 KB
    __shared__ float sel_w[FR * 16];   // 8 KB

    const int t = threadIdx.x;
    const int l = t & 63;
    const int w = __builtin_amdgcn_readfirstlane((int)(t >> 6));  // 0..3
    const int row0 = blockIdx.x * FR;
    const int k = *topk_p;

    // stage scores (coalesced read, rotated scatter: col c at (c+r)&63)
    {
#pragma unroll
        for (int i = 0; i < (FR * NM / 4) / 256; ++i) {    // 8 iters
            const int idx = i * 256 + t;                   // float4 index
            const int r = idx >> 4, c4 = idx & 15;
            int gr = row0 + r; if (gr > M - 1) gr = M - 1;
            const float4 v = *reinterpret_cast<const float4*>(
                &out_attn[(size_t)gr * NM + c4 * 4]);
            s_lds[r * NM + ((c4 * 4 + 0 + r) & 63)] = v.x;
            s_lds[r * NM + ((c4 * 4 + 1 + r) & 63)] = v.y;
            s_lds[r * NM + ((c4 * 4 + 2 + r) & 63)] = v.z;
            s_lds[r * NM + ((c4 * 4 + 3 + r) & 63)] = v.w;
        }
    }
    __syncthreads();

    // ---- per-row top-k: thread t handles row t (t < FR)
    if (t < FR) {
        const int r = t;
        float sv[NM];
#pragma unroll
        for (int n = 0; n < NM; ++n) sv[n] = s_lds[r * NM + ((n + r) & 63)];

        if (k < NM) {
            const int kk = k < 16 ? k : 16;   // dataset: k = 8
            u64 taken = 0ull;
            float mmax = 0.f, Z = 0.f;
            for (int i = 0; i < kk; ++i) {
                float m = -1.0e30f;
                int idx = 0;
#pragma unroll
                for (int n = 0; n < NM; ++n) {
                    const bool avail  = ((taken >> n) & 1ull) == 0ull;
                    const bool better = avail && (sv[n] > m);  // strict >: lowest idx ties
                    m   = better ? sv[n] : m;
                    idx = better ? n : idx;
                }
                taken |= (1ull << idx);
                if (i == 0) mmax = m;
                const float wv = expf(m - mmax);
                Z += wv;
                sel_i[r * 16 + i] = idx;
                sel_w[r * 16 + i] = wv;
            }
#pragma unroll
            for (int n = 0; n < NM; ++n) s_lds[r * NM + ((n + r) & 63)] = 0.f;
            for (int i = 0; i < kk; ++i) {
                const float wz = sel_w[r * 16 + i] / Z;
                sel_w[r * 16 + i] = wz;
                s_lds[r * NM + ((sel_i[r * 16 + i] + r) & 63)] = wz;
            }
        } else {
            float m = -1.0e30f;
#pragma unroll
            for (int n = 0; n < NM; ++n) m = sv[n] > m ? sv[n] : m;
            float Z = 0.f;
#pragma unroll
            for (int n = 0; n < NM; ++n) Z += expf(sv[n] - m);
#pragma unroll
            for (int n = 0; n < NM; ++n) s_lds[r * NM + ((n + r) & 63)] = expf(sv[n] - m) / Z;
        }
    }
    __syncthreads();

    // ---- attn stores (coalesced)
#pragma unroll
    for (int i = 0; i < (FR * NM) / 256; ++i) {    // 32 iters
        const int idx = i * 256 + t;
        const int r = idx >> 6, n = idx & 63;
        const int grow = row0 + r;
        if (grow < M) out_attn[(size_t)grow * NM + n] = s_lds[r * NM + ((n + r) & 63)];
    }

    // ---- retrieved (PV): wave w rows [32w, 32w+32); lane l = d-quad
    {
        const float4* mem4 = reinterpret_cast<const float4*>(mem);   // [NM][64]
        const int kk = k < 16 ? k : 16;
#pragma unroll 1
        for (int rr = 0; rr < FR / 4; ++rr) {
            const int r    = w * (FR / 4) + rr;
            const int grow = row0 + r;
            if (grow >= M) continue;
            float4 acc; acc.x = 0.f; acc.y = 0.f; acc.z = 0.f; acc.w = 0.f;
            if (k < NM) {
                for (int i = 0; i < kk; ++i) {
                    const int   mi = sel_i[r * 16 + i];      // uniform ds
                    const float wz = sel_w[r * 16 + i];
                    const float4 mv = mem4[mi * 64 + l];     // coalesced, L1-hot
                    acc.x = fmaf(wz, mv.x, acc.x);           // rank-ascending chain
                    acc.y = fmaf(wz, mv.y, acc.y);
                    acc.z = fmaf(wz, mv.z, acc.z);
                    acc.w = fmaf(wz, mv.w, acc.w);
                }
            } else {
                for (int n = 0; n < NM; ++n) {
                    const float wz = s_lds[r * NM + ((n + r) & 63)];
                    const float4 mv = mem4[n * 64 + l];
                    acc.x = fmaf(wz, mv.x, acc.x);           // n-ascending chain
                    acc.y = fmaf(wz, mv.y, acc.y);
                    acc.z = fmaf(wz, mv.z, acc.z);
                    acc.w = fmaf(wz, mv.w, acc.w);
                }
            }
            *reinterpret_cast<float4*>(&out_ret[(size_t)grow * DD + 4 * l]) = acc;
        }
    }
}

// ---------------------------------------------------------------------------
extern "C" void kernel_launch(void* const* d_in, const int* in_sizes, int n_in,
                              void* d_out, int out_size, void* d_ws, size_t ws_size,
                              hipStream_t stream) {
    const float* query      = (const float*)d_in[0];
    const float* memory     = (const float*)d_in[1];
    const float* importance = (const float*)d_in[2];
    const float* age        = (const float*)d_in[3];
    const float* Wq         = (const float*)d_in[4];
    const float* Wk         = (const float*)d_in[5];
    const int*   topk       = (const int*)d_in[6];

    const int M = in_sizes[0] / DD;   // B*S = 131072

    float* kT4  = (float*)d_ws;                      // 64 KB [og][n][4]
    float* bias = kT4 + (size_t)DD * NM;             // [NM]
    float* wqt  = bias + 64;                         // [DD][DD] = 256 KB
    float* wkt  = wqt + (size_t)DD * DD;             // [DD][DD] = 256 KB

    hipLaunchKernelGGL(prep_tr, dim3(DD, 2), dim3(DD), 0, stream,
                       Wq, Wk, wqt, wkt);
    hipLaunchKernelGGL(prep_kT, dim3(NM), dim3(DD), 0, stream,
                       memory, wkt, importance, age, kT4, bias);

    float* out_ret  = (float*)d_out;
    float* out_attn = out_ret + (size_t)M * DD;

    // q staged through out_ret; raw scores staged through out_attn.
    // fin3 reads its own rows of both before overwriting them.
    hipLaunchKernelGGL(qgemm4, dim3((M + 31) / 32), dim3(256), 0, stream,
                       query, (const float4*)wqt, out_ret, M);
    hipLaunchKernelGGL(scores_k, dim3((M + 31) / 32), dim3(256), 0, stream,
                       out_ret, (const float4*)kT4, bias, out_attn, M);
    hipLaunchKernelGGL(fin3, dim3((M + FR - 1) / FR), dim3(256), 0, stream,
                       memory, topk, out_ret, out_attn, M);
}